// Round 17
// baseline (614.125 us; speedup 1.0000x reference)
//
#include <hip/hip_runtime.h>

#define DIM   64
#define HID   256
#define TLEN  21
#define BS    65536
#define BLOCK 512
#define WAVES 8
#define ROWS_PER_WAVE 16
#define ROWS_PER_BLOCK 128              // 8 waves * 16 rows
#define NBLOCKS (BS / ROWS_PER_BLOCK)   // 512 -> 2 blocks/CU (LDS ~65 KB)

typedef __bf16    bf16x8   __attribute__((ext_vector_type(8)));
typedef float     f32x16   __attribute__((ext_vector_type(16)));
typedef float     f32x4    __attribute__((ext_vector_type(4)));
typedef unsigned  uint32x4 __attribute__((ext_vector_type(4)));

__device__ __forceinline__ bf16x8 as_bf16x8(uint32x4 u) {
    return __builtin_bit_cast(bf16x8, u);
}

__device__ __forceinline__ unsigned pack2(float a, float b) {
    __bf16 x = (__bf16)a, y = (__bf16)b;
    unsigned short ux = __builtin_bit_cast(unsigned short, x);
    unsigned short uy = __builtin_bit_cast(unsigned short, y);
    return (unsigned)ux | ((unsigned)uy << 16);
}

// ---------------------------------------------------------------------------
// Round-17: trans-free-ish tanh. R16's counters: VALU 67% + MFMA 29% = 96%
// issue-port saturation, and the VALU-cycle invariant (~320 us across
// R14-R16) back-solves to ~16 cyc per transcendental op -> the 128 trans
// ops/feval (64 tanh x {exp2, rcp}) are ~85% of all VALU cycles.
// Fix: Pade[5/4] tanh = x(945+105r+r^2)/(945+420r+15r^2), r=x^2, input
// clamped to +-3.65 (where the rational crosses 1.0 -> no output clamp).
// Max abs err ~1.3e-3 (below bf16 quantization 4e-3). The division's rcp is
// SHARED between two activations: 1/da = db*rcp(da*db), 1/db = da*rcp(..)
// -> trans ops per pair: 4 -> 1. Weight pre-scaling reverted to 1x.
// ---------------------------------------------------------------------------
__device__ __forceinline__ float pade_num(float x) {   // x*(945 + 105r + r^2)
    float r = x * x;
    return x * fmaf(r, r + 105.0f, 945.0f);
}
__device__ __forceinline__ float pade_den(float x) {   // 945 + 420r + 15r^2
    float r = x * x;
    return fmaf(r, fmaf(r, 15.0f, 420.0f), 945.0f);
}
__device__ __forceinline__ unsigned tanh2_pk(float a, float b) {
    a = fminf(fmaxf(a, -3.65f), 3.65f);
    b = fminf(fmaxf(b, -3.65f), 3.65f);
    float na = pade_num(a), nb = pade_num(b);
    float da = pade_den(a), db = pade_den(b);
    float rr = __builtin_amdgcn_rcpf(da * db);
    return pack2(na * (db * rr), nb * (da * rr));
}

// Inline-asm LDS reads: LICM-proof (R12: fixed the 8.26 GB scratch storm)
// and batchable with counted waits (R15: 2.15x). DO NOT convert back to
// plain loads (LICM) or volatile (serializing).
template<int OFF>
__device__ __forceinline__ uint32x4 ds128(unsigned base) {
    uint32x4 d;
    asm volatile("ds_read_b128 %0, %1 offset:%c2"
                 : "=v"(d) : "v"(base), "i"(OFF) : "memory");
    return d;
}
template<int K>
__device__ __forceinline__ void wait_lgkm() {
    asm volatile("s_waitcnt lgkmcnt(%c0)" :: "i"(K) : "memory");
    __builtin_amdgcn_sched_barrier(0);
}
__device__ __forceinline__ unsigned lds_base(const void* p) {
    return (unsigned)(unsigned long long)p;   // low 32 bits = LDS offset (gfx9+)
}

__device__ __forceinline__ f32x4 mfma16(bf16x8 a, bf16x8 b, f32x4 c) {
    return __builtin_amdgcn_mfma_f32_16x16x32_bf16(a, b, c, 0, 0, 0);
}

struct A1Buf { uint32x4 a0, a1, a2, a3, b0, b1; };   // A1 quad + b1 pair [6]
struct A2Buf { uint32x4 a0, a1, a2, a3; };           // A2 quad [4]

template<int N>
__device__ __forceinline__ void issue_a1b1(unsigned a1b, unsigned b1b, A1Buf& g) {
    g.a0 = ds128<(4 * N + 0) * 1024>(a1b);
    g.a1 = ds128<(4 * N + 1) * 1024>(a1b);
    g.a2 = ds128<(4 * N + 2) * 1024>(a1b);
    g.a3 = ds128<(4 * N + 3) * 1024>(a1b);
    g.b0 = ds128<(2 * N) * 64>(b1b);
    g.b1 = ds128<(2 * N + 1) * 64>(b1b);
}
template<int N>
__device__ __forceinline__ void issue_a2(unsigned a2b, A2Buf& g) {
    g.a0 = ds128<(0 * 8 + N) * 1024>(a2b);
    g.a1 = ds128<(1 * 8 + N) * 1024>(a2b);
    g.a2 = ds128<(2 * 8 + N) * 1024>(a2b);
    g.a3 = ds128<(3 * 8 + N) * 1024>(a2b);
}

// One pipelined kt2 iteration (consumes cur*, prefetches into nxt*).
// Wait ledger as R16 (verified): counted lgkmcnt keeps prefetches in flight.
template<int N>
__device__ __forceinline__ void kt2_pipe(unsigned a1b, unsigned a2b, unsigned b1b,
                                         A1Buf& cur1, A1Buf& nxt1,
                                         A2Buf& cur2, A2Buf& nxt2,
                                         bf16x8 bk0, bf16x8 bk1,
                                         f32x4& d20, f32x4& d21,
                                         f32x4& d22, f32x4& d23)
{
    if constexpr (N < 7) issue_a1b1<N + 1>(a1b, b1b, nxt1);
    wait_lgkm<N < 7 ? 10 : 4>();
    f32x4 d1e = __builtin_bit_cast(f32x4, cur1.b0);
    f32x4 d1o = __builtin_bit_cast(f32x4, cur1.b1);
    d1e = mfma16(as_bf16x8(cur1.a0), bk0, d1e);
    d1e = mfma16(as_bf16x8(cur1.a1), bk1, d1e);
    d1o = mfma16(as_bf16x8(cur1.a2), bk0, d1o);
    d1o = mfma16(as_bf16x8(cur1.a3), bk1, d1o);

    if constexpr (N < 7) issue_a2<N + 1>(a2b, nxt2);

    uint32x4 bt;
    bt[0] = tanh2_pk(d1e[0], d1e[1]);
    bt[1] = tanh2_pk(d1e[2], d1e[3]);
    bt[2] = tanh2_pk(d1o[0], d1o[1]);
    bt[3] = tanh2_pk(d1o[2], d1o[3]);
    bf16x8 btb = as_bf16x8(bt);

    wait_lgkm<N < 7 ? 10 : 0>();
    d20 = mfma16(as_bf16x8(cur2.a0), btb, d20);
    d21 = mfma16(as_bf16x8(cur2.a1), btb, d21);
    d22 = mfma16(as_bf16x8(cur2.a2), btb, d22);
    d23 = mfma16(as_bf16x8(cur2.a3), btb, d23);
}

// feval fragment machinery verified (absmax 0.03125 since R10):
//   mfma_f32_16x16x32_bf16 swapped chain; C/D col=lane&15, row=4*(lane>>4)+reg
//   k-slot map P(q,j)=4q+(j&3)+16*(j>>2) on both A (LDS-prepermuted) and B
//   (packed from C/D-ordered regs) self-cancels; biases natural order.
__device__ __forceinline__ f32x16 feval(unsigned a1b, unsigned a2b,
                                        unsigned b1b, unsigned b2b,
                                        uint32x4 bkA, uint32x4 bkB)
{
    bf16x8 bk0 = as_bf16x8(bkA);
    bf16x8 bk1 = as_bf16x8(bkB);

    uint32x4 u0 = ds128<0>(b2b);
    uint32x4 u1 = ds128<64>(b2b);
    uint32x4 u2 = ds128<128>(b2b);
    uint32x4 u3 = ds128<192>(b2b);

    A1Buf g0, g1;
    A2Buf h0, h1;
    issue_a1b1<0>(a1b, b1b, g0);
    issue_a2<0>(a2b, h0);
    wait_lgkm<10>();                       // retire b2 (out: G0a+G0b = 10)
    f32x4 d20 = __builtin_bit_cast(f32x4, u0);
    f32x4 d21 = __builtin_bit_cast(f32x4, u1);
    f32x4 d22 = __builtin_bit_cast(f32x4, u2);
    f32x4 d23 = __builtin_bit_cast(f32x4, u3);

    kt2_pipe<0>(a1b, a2b, b1b, g0, g1, h0, h1, bk0, bk1, d20, d21, d22, d23);
    kt2_pipe<1>(a1b, a2b, b1b, g1, g0, h1, h0, bk0, bk1, d20, d21, d22, d23);
    kt2_pipe<2>(a1b, a2b, b1b, g0, g1, h0, h1, bk0, bk1, d20, d21, d22, d23);
    kt2_pipe<3>(a1b, a2b, b1b, g1, g0, h1, h0, bk0, bk1, d20, d21, d22, d23);
    kt2_pipe<4>(a1b, a2b, b1b, g0, g1, h0, h1, bk0, bk1, d20, d21, d22, d23);
    kt2_pipe<5>(a1b, a2b, b1b, g1, g0, h1, h0, bk0, bk1, d20, d21, d22, d23);
    kt2_pipe<6>(a1b, a2b, b1b, g0, g1, h0, h1, bk0, bk1, d20, d21, d22, d23);
    kt2_pipe<7>(a1b, a2b, b1b, g1, g0, h1, h0, bk0, bk1, d20, d21, d22, d23);

    f32x16 k;
    #pragma unroll
    for (int i = 0; i < 4; i++) {
        k[i]      = d20[i];
        k[4 + i]  = d21[i];
        k[8 + i]  = d22[i];
        k[12 + i] = d23[i];
    }
    return k;
}

__device__ __forceinline__ uint32x4 pack_lo(f32x16 v) {
    uint32x4 r;
    r[0] = pack2(v[0], v[1]); r[1] = pack2(v[2], v[3]);
    r[2] = pack2(v[4], v[5]); r[3] = pack2(v[6], v[7]);
    return r;
}
__device__ __forceinline__ uint32x4 pack_hi(f32x16 v) {
    uint32x4 r;
    r[0] = pack2(v[8], v[9]);   r[1] = pack2(v[10], v[11]);
    r[2] = pack2(v[12], v[13]); r[3] = pack2(v[14], v[15]);
    return r;
}
__device__ __forceinline__ uint32x4 packaxpy_lo(float c, f32x16 k, f32x16 z) {
    uint32x4 r;
    r[0] = pack2(fmaf(c, k[0], z[0]), fmaf(c, k[1], z[1]));
    r[1] = pack2(fmaf(c, k[2], z[2]), fmaf(c, k[3], z[3]));
    r[2] = pack2(fmaf(c, k[4], z[4]), fmaf(c, k[5], z[5]));
    r[3] = pack2(fmaf(c, k[6], z[6]), fmaf(c, k[7], z[7]));
    return r;
}
__device__ __forceinline__ uint32x4 packaxpy_hi(float c, f32x16 k, f32x16 z) {
    uint32x4 r;
    r[0] = pack2(fmaf(c, k[8],  z[8]),  fmaf(c, k[9],  z[9]));
    r[1] = pack2(fmaf(c, k[10], z[10]), fmaf(c, k[11], z[11]));
    r[2] = pack2(fmaf(c, k[12], z[12]), fmaf(c, k[13], z[13]));
    r[3] = pack2(fmaf(c, k[14], z[14]), fmaf(c, k[15], z[15]));
    return r;
}
__device__ __forceinline__ f32x16 axpy16(float c, f32x16 k, f32x16 z) {
    f32x16 r;
    #pragma unroll
    for (int i = 0; i < 16; i++) r[i] = fmaf(c, k[i], z[i]);
    return r;
}

extern "C" __global__ __launch_bounds__(BLOCK, 1) void node_mfma_kernel(
    const float* __restrict__ z0, const float* __restrict__ tarr,
    const float* __restrict__ W1, const float* __restrict__ b1,
    const float* __restrict__ W2, const float* __restrict__ b2,
    float* __restrict__ out)
{
    __shared__ __align__(16) unsigned short sA1[32 * 64 * 8];   // 32 KiB
    __shared__ __align__(16) unsigned short sA2[32 * 64 * 8];   // 32 KiB
    __shared__ __align__(16) float sb1[HID];                    // natural order
    __shared__ __align__(16) float sb2[DIM];
    // total LDS ~65.3 KB -> 2 blocks/CU

    const int tid  = threadIdx.x;
    const int lane = tid & 63;
    const int wv   = tid >> 6;
    const int q    = lane >> 4;
    const int bcol = lane & 15;

    // ---- stage W1 fragments (unscaled — Pade takes raw pre-activation) ----
    for (int idx = tid; idx < DIM * HID; idx += BLOCK) {
        int hid = idx & (HID - 1);
        int dim = idx >> 8;
        int ht = hid >> 4, row = hid & 15;
        int kt = dim >> 5, dlo = dim & 31;
        int j  = (dlo & 3) | ((dlo >> 4) << 2);
        int qq = (dlo >> 2) & 3;
        __bf16 bv = (__bf16)W1[idx];
        sA1[((ht * 2 + kt) * 64 + qq * 16 + row) * 8 + j] =
            __builtin_bit_cast(unsigned short, bv);
    }
    // ---- stage W2 fragments ----
    for (int idx = tid; idx < HID * DIM; idx += BLOCK) {
        int dim = idx & (DIM - 1);
        int hid = idx >> 6;
        int mt  = dim >> 4, row = dim & 15;
        int kt2 = hid >> 5, hlo = hid & 31;
        int j   = (hlo & 3) | ((hlo >> 4) << 2);
        int qq  = (hlo >> 2) & 3;
        __bf16 bv = (__bf16)W2[idx];
        sA2[((mt * 8 + kt2) * 64 + qq * 16 + row) * 8 + j] =
            __builtin_bit_cast(unsigned short, bv);
    }
    if (tid < HID) sb1[tid] = b1[tid];
    if (tid < DIM) sb2[tid] = b2[tid];

    // ---- out[0] = z0 (coalesced block-slice copy) ----
    {
        const f32x4* src = reinterpret_cast<const f32x4*>(z0 + (size_t)blockIdx.x * ROWS_PER_BLOCK * DIM);
        f32x4*       dst = reinterpret_cast<f32x4*>(out + (size_t)blockIdx.x * ROWS_PER_BLOCK * DIM);
        for (int i = tid; i < ROWS_PER_BLOCK * DIM / 4; i += BLOCK) dst[i] = src[i];
    }

    __syncthreads();

    const int rowbase = blockIdx.x * ROWS_PER_BLOCK + wv * ROWS_PER_WAVE;
    const size_t myrow = (size_t)(rowbase + bcol) * DIM;

    const unsigned a1b = lds_base(sA1) + lane * 16;
    const unsigned a2b = lds_base(sA2) + lane * 16;
    const unsigned b1b = lds_base(sb1) + q * 16;
    const unsigned b2b = lds_base(sb2) + q * 16;

    // ---- z0 -> za registers directly (za[mt*4+r] = z[bcol][16mt+4q+r]) ----
    f32x16 za;
    #pragma unroll
    for (int mt = 0; mt < 4; mt++) {
        f32x4 v = *reinterpret_cast<const f32x4*>(z0 + myrow + mt * 16 + 4 * q);
        za[mt * 4 + 0] = v[0]; za[mt * 4 + 1] = v[1];
        za[mt * 4 + 2] = v[2]; za[mt * 4 + 3] = v[3];
    }

    #pragma unroll 1
    for (int s = 0; s < TLEN - 1; s++) {
        const float h  = tarr[s + 1] - tarr[s];
        const float h2 = 0.5f * h;
        const float h3 = h * (1.0f / 3.0f);
        const float h6 = h * (1.0f / 6.0f);

        f32x16 k1 = feval(a1b, a2b, b1b, b2b, pack_lo(za), pack_hi(za));
        f32x16 zf = axpy16(h6, k1, za);

        f32x16 k2 = feval(a1b, a2b, b1b, b2b,
                          packaxpy_lo(h2, k1, za), packaxpy_hi(h2, k1, za));
        zf = axpy16(h3, k2, zf);

        f32x16 k3 = feval(a1b, a2b, b1b, b2b,
                          packaxpy_lo(h2, k2, za), packaxpy_hi(h2, k2, za));
        zf = axpy16(h3, k3, zf);

        f32x16 k4 = feval(a1b, a2b, b1b, b2b,
                          packaxpy_lo(h, k3, za), packaxpy_hi(h, k3, za));
        za = axpy16(h6, k4, zf);

        // ---- trajectory[s+1]: direct strided dwordx4 stores (L2 merges) ----
        float* obase = out + (size_t)(s + 1) * BS * DIM + myrow;
        #pragma unroll
        for (int mt = 0; mt < 4; mt++) {
            f32x4 v;
            v[0] = za[mt * 4 + 0]; v[1] = za[mt * 4 + 1];
            v[2] = za[mt * 4 + 2]; v[3] = za[mt * 4 + 3];
            *reinterpret_cast<f32x4*>(obase + mt * 16 + 4 * q) = v;
        }
    }
}

extern "C" void kernel_launch(void* const* d_in, const int* in_sizes, int n_in,
                              void* d_out, int out_size, void* d_ws, size_t ws_size,
                              hipStream_t stream) {
    const float* z0 = (const float*)d_in[0];
    const float* t  = (const float*)d_in[1];
    const float* W1 = (const float*)d_in[2];
    const float* b1 = (const float*)d_in[3];
    const float* W2 = (const float*)d_in[4];
    const float* b2 = (const float*)d_in[5];
    float* out = (float*)d_out;

    node_mfma_kernel<<<dim3(NBLOCKS), dim3(BLOCK), 0, stream>>>(
        z0, t, W1, b1, W2, b2, out);
}

// Round 18
// 433.644 us; speedup vs baseline: 1.4162x; 1.4162x over previous
//
#include <hip/hip_runtime.h>

#define DIM   64
#define HID   256
#define TLEN  21
#define BS    65536
#define BLOCK 512
#define WAVES 8
#define ROWS_PER_WAVE 16
#define ROWS_PER_BLOCK 128              // 8 waves * 16 rows
#define NBLOCKS (BS / ROWS_PER_BLOCK)   // 512 -> 2 blocks/CU (LDS ~65 KB)

typedef __bf16    bf16x8   __attribute__((ext_vector_type(8)));
typedef float     f32x16   __attribute__((ext_vector_type(16)));
typedef float     f32x4    __attribute__((ext_vector_type(4)));
typedef unsigned  uint32x4 __attribute__((ext_vector_type(4)));

__device__ __forceinline__ bf16x8 as_bf16x8(uint32x4 u) {
    return __builtin_bit_cast(bf16x8, u);
}

// ---------------------------------------------------------------------------
// Round-18: single-instruction bf16 pair-pack. R17's failed Pade experiment
// calibrated per-op cost and exposed ~1500 unexplained VALU ops/step/wave:
// the scalar (__bf16) casts in pack2 lower to multi-op RTNE sequences that
// the compiler does not fuse. gfx950 has v_cvt_pk_bf16_f32 (2 f32 -> 2 bf16
// in ONE instruction; no builtin, asm per guide T12). Non-volatile asm, no
// clobbers -> remains schedulable (avoids m240's hand-asm penalty mode).
// Everything else = R16 exactly (476 us, absmax 0.03125).
// ---------------------------------------------------------------------------
__device__ __forceinline__ unsigned pack2(float a, float b) {
    unsigned r;
    asm("v_cvt_pk_bf16_f32 %0, %1, %2" : "=v"(r) : "v"(a), "v"(b));
    return r;
}

// W1/b1 pre-scaled by 2*log2(e): tanh(y) = fmaf(-2, rcp(exp2(x)+1), 1).
// Saturation exact at +-inf. Validated R13-R16 (absmax 0.03125).
__device__ __forceinline__ float tanh_2x(float x) {
    float e = __builtin_amdgcn_exp2f(x);
    float r = __builtin_amdgcn_rcpf(e + 1.0f);
    return fmaf(-2.0f, r, 1.0f);
}

// Inline-asm LDS reads: LICM-proof (R12: fixed the 8.26 GB scratch storm)
// and batchable with counted waits (R15: 2.15x). DO NOT convert back to
// plain loads (LICM) or volatile (serializing).
template<int OFF>
__device__ __forceinline__ uint32x4 ds128(unsigned base) {
    uint32x4 d;
    asm volatile("ds_read_b128 %0, %1 offset:%c2"
                 : "=v"(d) : "v"(base), "i"(OFF) : "memory");
    return d;
}
template<int K>
__device__ __forceinline__ void wait_lgkm() {
    asm volatile("s_waitcnt lgkmcnt(%c0)" :: "i"(K) : "memory");
    __builtin_amdgcn_sched_barrier(0);
}
__device__ __forceinline__ unsigned lds_base(const void* p) {
    return (unsigned)(unsigned long long)p;   // low 32 bits = LDS offset (gfx9+)
}

__device__ __forceinline__ f32x4 mfma16(bf16x8 a, bf16x8 b, f32x4 c) {
    return __builtin_amdgcn_mfma_f32_16x16x32_bf16(a, b, c, 0, 0, 0);
}

struct A1Buf { uint32x4 a0, a1, a2, a3, b0, b1; };   // A1 quad + b1 pair [6]
struct A2Buf { uint32x4 a0, a1, a2, a3; };           // A2 quad [4]

template<int N>
__device__ __forceinline__ void issue_a1b1(unsigned a1b, unsigned b1b, A1Buf& g) {
    g.a0 = ds128<(4 * N + 0) * 1024>(a1b);
    g.a1 = ds128<(4 * N + 1) * 1024>(a1b);
    g.a2 = ds128<(4 * N + 2) * 1024>(a1b);
    g.a3 = ds128<(4 * N + 3) * 1024>(a1b);
    g.b0 = ds128<(2 * N) * 64>(b1b);
    g.b1 = ds128<(2 * N + 1) * 64>(b1b);
}
template<int N>
__device__ __forceinline__ void issue_a2(unsigned a2b, A2Buf& g) {
    g.a0 = ds128<(0 * 8 + N) * 1024>(a2b);
    g.a1 = ds128<(1 * 8 + N) * 1024>(a2b);
    g.a2 = ds128<(2 * 8 + N) * 1024>(a2b);
    g.a3 = ds128<(3 * 8 + N) * 1024>(a2b);
}

// One pipelined kt2 iteration (consumes cur*, prefetches into nxt*).
// Wait ledger verified R16: counted lgkmcnt keeps prefetches in flight.
template<int N>
__device__ __forceinline__ void kt2_pipe(unsigned a1b, unsigned a2b, unsigned b1b,
                                         A1Buf& cur1, A1Buf& nxt1,
                                         A2Buf& cur2, A2Buf& nxt2,
                                         bf16x8 bk0, bf16x8 bk1,
                                         f32x4& d20, f32x4& d21,
                                         f32x4& d22, f32x4& d23)
{
    if constexpr (N < 7) issue_a1b1<N + 1>(a1b, b1b, nxt1);
    wait_lgkm<N < 7 ? 10 : 4>();
    f32x4 d1e = __builtin_bit_cast(f32x4, cur1.b0);
    f32x4 d1o = __builtin_bit_cast(f32x4, cur1.b1);
    d1e = mfma16(as_bf16x8(cur1.a0), bk0, d1e);
    d1e = mfma16(as_bf16x8(cur1.a1), bk1, d1e);
    d1o = mfma16(as_bf16x8(cur1.a2), bk0, d1o);
    d1o = mfma16(as_bf16x8(cur1.a3), bk1, d1o);

    if constexpr (N < 7) issue_a2<N + 1>(a2b, nxt2);

    uint32x4 bt;
    bt[0] = pack2(tanh_2x(d1e[0]), tanh_2x(d1e[1]));
    bt[1] = pack2(tanh_2x(d1e[2]), tanh_2x(d1e[3]));
    bt[2] = pack2(tanh_2x(d1o[0]), tanh_2x(d1o[1]));
    bt[3] = pack2(tanh_2x(d1o[2]), tanh_2x(d1o[3]));
    bf16x8 btb = as_bf16x8(bt);

    wait_lgkm<N < 7 ? 10 : 0>();
    d20 = mfma16(as_bf16x8(cur2.a0), btb, d20);
    d21 = mfma16(as_bf16x8(cur2.a1), btb, d21);
    d22 = mfma16(as_bf16x8(cur2.a2), btb, d22);
    d23 = mfma16(as_bf16x8(cur2.a3), btb, d23);
}

// feval fragment machinery verified (absmax 0.03125 since R10):
//   mfma_f32_16x16x32_bf16 swapped chain; C/D col=lane&15, row=4*(lane>>4)+reg
//   k-slot map P(q,j)=4q+(j&3)+16*(j>>2) on both A (LDS-prepermuted) and B
//   (packed from C/D-ordered regs) self-cancels; biases natural order.
__device__ __forceinline__ f32x16 feval(unsigned a1b, unsigned a2b,
                                        unsigned b1b, unsigned b2b,
                                        uint32x4 bkA, uint32x4 bkB)
{
    bf16x8 bk0 = as_bf16x8(bkA);
    bf16x8 bk1 = as_bf16x8(bkB);

    uint32x4 u0 = ds128<0>(b2b);
    uint32x4 u1 = ds128<64>(b2b);
    uint32x4 u2 = ds128<128>(b2b);
    uint32x4 u3 = ds128<192>(b2b);

    A1Buf g0, g1;
    A2Buf h0, h1;
    issue_a1b1<0>(a1b, b1b, g0);
    issue_a2<0>(a2b, h0);
    wait_lgkm<10>();                       // retire b2 (out: G0a+G0b = 10)
    f32x4 d20 = __builtin_bit_cast(f32x4, u0);
    f32x4 d21 = __builtin_bit_cast(f32x4, u1);
    f32x4 d22 = __builtin_bit_cast(f32x4, u2);
    f32x4 d23 = __builtin_bit_cast(f32x4, u3);

    kt2_pipe<0>(a1b, a2b, b1b, g0, g1, h0, h1, bk0, bk1, d20, d21, d22, d23);
    kt2_pipe<1>(a1b, a2b, b1b, g1, g0, h1, h0, bk0, bk1, d20, d21, d22, d23);
    kt2_pipe<2>(a1b, a2b, b1b, g0, g1, h0, h1, bk0, bk1, d20, d21, d22, d23);
    kt2_pipe<3>(a1b, a2b, b1b, g1, g0, h1, h0, bk0, bk1, d20, d21, d22, d23);
    kt2_pipe<4>(a1b, a2b, b1b, g0, g1, h0, h1, bk0, bk1, d20, d21, d22, d23);
    kt2_pipe<5>(a1b, a2b, b1b, g1, g0, h1, h0, bk0, bk1, d20, d21, d22, d23);
    kt2_pipe<6>(a1b, a2b, b1b, g0, g1, h0, h1, bk0, bk1, d20, d21, d22, d23);
    kt2_pipe<7>(a1b, a2b, b1b, g1, g0, h1, h0, bk0, bk1, d20, d21, d22, d23);

    f32x16 k;
    #pragma unroll
    for (int i = 0; i < 4; i++) {
        k[i]      = d20[i];
        k[4 + i]  = d21[i];
        k[8 + i]  = d22[i];
        k[12 + i] = d23[i];
    }
    return k;
}

__device__ __forceinline__ uint32x4 pack_lo(f32x16 v) {
    uint32x4 r;
    r[0] = pack2(v[0], v[1]); r[1] = pack2(v[2], v[3]);
    r[2] = pack2(v[4], v[5]); r[3] = pack2(v[6], v[7]);
    return r;
}
__device__ __forceinline__ uint32x4 pack_hi(f32x16 v) {
    uint32x4 r;
    r[0] = pack2(v[8], v[9]);   r[1] = pack2(v[10], v[11]);
    r[2] = pack2(v[12], v[13]); r[3] = pack2(v[14], v[15]);
    return r;
}
__device__ __forceinline__ uint32x4 packaxpy_lo(float c, f32x16 k, f32x16 z) {
    uint32x4 r;
    r[0] = pack2(fmaf(c, k[0], z[0]), fmaf(c, k[1], z[1]));
    r[1] = pack2(fmaf(c, k[2], z[2]), fmaf(c, k[3], z[3]));
    r[2] = pack2(fmaf(c, k[4], z[4]), fmaf(c, k[5], z[5]));
    r[3] = pack2(fmaf(c, k[6], z[6]), fmaf(c, k[7], z[7]));
    return r;
}
__device__ __forceinline__ uint32x4 packaxpy_hi(float c, f32x16 k, f32x16 z) {
    uint32x4 r;
    r[0] = pack2(fmaf(c, k[8],  z[8]),  fmaf(c, k[9],  z[9]));
    r[1] = pack2(fmaf(c, k[10], z[10]), fmaf(c, k[11], z[11]));
    r[2] = pack2(fmaf(c, k[12], z[12]), fmaf(c, k[13], z[13]));
    r[3] = pack2(fmaf(c, k[14], z[14]), fmaf(c, k[15], z[15]));
    return r;
}
__device__ __forceinline__ f32x16 axpy16(float c, f32x16 k, f32x16 z) {
    f32x16 r;
    #pragma unroll
    for (int i = 0; i < 16; i++) r[i] = fmaf(c, k[i], z[i]);
    return r;
}

extern "C" __global__ __launch_bounds__(BLOCK, 1) void node_mfma_kernel(
    const float* __restrict__ z0, const float* __restrict__ tarr,
    const float* __restrict__ W1, const float* __restrict__ b1,
    const float* __restrict__ W2, const float* __restrict__ b2,
    float* __restrict__ out)
{
    __shared__ __align__(16) unsigned short sA1[32 * 64 * 8];   // 32 KiB
    __shared__ __align__(16) unsigned short sA2[32 * 64 * 8];   // 32 KiB
    __shared__ __align__(16) float sb1[HID];                    // x 2*log2e
    __shared__ __align__(16) float sb2[DIM];
    // total LDS ~65.3 KB -> 2 blocks/CU

    const int tid  = threadIdx.x;
    const int lane = tid & 63;
    const int wv   = tid >> 6;
    const int q    = lane >> 4;
    const int bcol = lane & 15;

    const float SC = 2.8853900817779268f;   // 2*log2(e)

    // ---- stage W1 fragments (pre-scaled): coalesced reads, P-permuted writes ----
    for (int idx = tid; idx < DIM * HID; idx += BLOCK) {
        int hid = idx & (HID - 1);
        int dim = idx >> 8;
        int ht = hid >> 4, row = hid & 15;
        int kt = dim >> 5, dlo = dim & 31;
        int j  = (dlo & 3) | ((dlo >> 4) << 2);
        int qq = (dlo >> 2) & 3;
        __bf16 bv = (__bf16)(SC * W1[idx]);
        sA1[((ht * 2 + kt) * 64 + qq * 16 + row) * 8 + j] =
            __builtin_bit_cast(unsigned short, bv);
    }
    // ---- stage W2 fragments ----
    for (int idx = tid; idx < HID * DIM; idx += BLOCK) {
        int dim = idx & (DIM - 1);
        int hid = idx >> 6;
        int mt  = dim >> 4, row = dim & 15;
        int kt2 = hid >> 5, hlo = hid & 31;
        int j   = (hlo & 3) | ((hlo >> 4) << 2);
        int qq  = (hlo >> 2) & 3;
        __bf16 bv = (__bf16)W2[idx];
        sA2[((mt * 8 + kt2) * 64 + qq * 16 + row) * 8 + j] =
            __builtin_bit_cast(unsigned short, bv);
    }
    if (tid < HID) sb1[tid] = SC * b1[tid];
    if (tid < DIM) sb2[tid] = b2[tid];

    // ---- out[0] = z0 (coalesced block-slice copy) ----
    {
        const f32x4* src = reinterpret_cast<const f32x4*>(z0 + (size_t)blockIdx.x * ROWS_PER_BLOCK * DIM);
        f32x4*       dst = reinterpret_cast<f32x4*>(out + (size_t)blockIdx.x * ROWS_PER_BLOCK * DIM);
        for (int i = tid; i < ROWS_PER_BLOCK * DIM / 4; i += BLOCK) dst[i] = src[i];
    }

    __syncthreads();

    const int rowbase = blockIdx.x * ROWS_PER_BLOCK + wv * ROWS_PER_WAVE;
    const size_t myrow = (size_t)(rowbase + bcol) * DIM;

    const unsigned a1b = lds_base(sA1) + lane * 16;
    const unsigned a2b = lds_base(sA2) + lane * 16;
    const unsigned b1b = lds_base(sb1) + q * 16;
    const unsigned b2b = lds_base(sb2) + q * 16;

    // ---- z0 -> za registers directly (za[mt*4+r] = z[bcol][16mt+4q+r]) ----
    f32x16 za;
    #pragma unroll
    for (int mt = 0; mt < 4; mt++) {
        f32x4 v = *reinterpret_cast<const f32x4*>(z0 + myrow + mt * 16 + 4 * q);
        za[mt * 4 + 0] = v[0]; za[mt * 4 + 1] = v[1];
        za[mt * 4 + 2] = v[2]; za[mt * 4 + 3] = v[3];
    }

    #pragma unroll 1
    for (int s = 0; s < TLEN - 1; s++) {
        const float h  = tarr[s + 1] - tarr[s];
        const float h2 = 0.5f * h;
        const float h3 = h * (1.0f / 3.0f);
        const float h6 = h * (1.0f / 6.0f);

        f32x16 k1 = feval(a1b, a2b, b1b, b2b, pack_lo(za), pack_hi(za));
        f32x16 zf = axpy16(h6, k1, za);

        f32x16 k2 = feval(a1b, a2b, b1b, b2b,
                          packaxpy_lo(h2, k1, za), packaxpy_hi(h2, k1, za));
        zf = axpy16(h3, k2, zf);

        f32x16 k3 = feval(a1b, a2b, b1b, b2b,
                          packaxpy_lo(h2, k2, za), packaxpy_hi(h2, k2, za));
        zf = axpy16(h3, k3, zf);

        f32x16 k4 = feval(a1b, a2b, b1b, b2b,
                          packaxpy_lo(h, k3, za), packaxpy_hi(h, k3, za));
        za = axpy16(h6, k4, zf);

        // ---- trajectory[s+1]: direct strided dwordx4 stores (L2 merges) ----
        float* obase = out + (size_t)(s + 1) * BS * DIM + myrow;
        #pragma unroll
        for (int mt = 0; mt < 4; mt++) {
            f32x4 v;
            v[0] = za[mt * 4 + 0]; v[1] = za[mt * 4 + 1];
            v[2] = za[mt * 4 + 2]; v[3] = za[mt * 4 + 3];
            *reinterpret_cast<f32x4*>(obase + mt * 16 + 4 * q) = v;
        }
    }
}

extern "C" void kernel_launch(void* const* d_in, const int* in_sizes, int n_in,
                              void* d_out, int out_size, void* d_ws, size_t ws_size,
                              hipStream_t stream) {
    const float* z0 = (const float*)d_in[0];
    const float* t  = (const float*)d_in[1];
    const float* W1 = (const float*)d_in[2];
    const float* b1 = (const float*)d_in[3];
    const float* W2 = (const float*)d_in[4];
    const float* b2 = (const float*)d_in[5];
    float* out = (float*)d_out;

    node_mfma_kernel<<<dim3(NBLOCKS), dim3(BLOCK), 0, stream>>>(
        z0, t, W1, b1, W2, b2, out);
}